// Round 11
// baseline (1545.718 us; speedup 1.0000x reference)
//
#include <hip/hip_runtime.h>

// ============================================================================
// CNN3_P r11: 1024-thread blocks for k_front and k_fc1 -> 4 waves/SIMD at
// 1 block/CU (both kernels were sum-of-pipes serialized at 2 waves/SIMD).
//  - front: 16-wave conv grids (conv1 GM2/GN8/NPW1, conv2/3 GM4/GN4/NPW2) —
//    same per-block LDS/A/MFMA totals as r4, double the latency hiding.
//  - fc1: M padded to 416 (26 mt), wave = 13mt x 1nt (GM2/GN8), acc=52 VGPR;
//    per-iter LDS reads 144->32 b128. S=16, N=128, dbuf lB, 1 barrier/iter.
//  - cvtpk (v_cvt_pk_bf16_f32) everywhere (r10 win).
// ============================================================================

typedef __attribute__((ext_vector_type(8))) short bf16x8;
typedef __attribute__((ext_vector_type(4))) float f32x4;
typedef __attribute__((ext_vector_type(8))) unsigned short u16x8;
typedef __attribute__((ext_vector_type(4))) unsigned short u16x4;
typedef __attribute__((ext_vector_type(2))) unsigned int u32x2;
typedef __attribute__((ext_vector_type(4))) unsigned int u32x4;

#define DEVINL __device__ __forceinline__

DEVINL unsigned short f2bf(float f) {
  unsigned u = __builtin_bit_cast(unsigned, f);
  return (unsigned short)((u + 0x7fffu + ((u >> 16) & 1u)) >> 16);  // RNE
}
DEVINL float bf2f(unsigned short h) {
  return __builtin_bit_cast(float, ((unsigned)h) << 16);
}
// packed f32x2 -> bf16x2 (RNE), lo -> bits[15:0]
DEVINL unsigned cvtpk(float lo, float hi) {
  unsigned r;
  asm("v_cvt_pk_bf16_f32 %0, %1, %2" : "=v"(r) : "v"(lo), "v"(hi));
  return r;
}
DEVINL f32x4 mfma16(bf16x8 a, bf16x8 b, f32x4 c) {
  return __builtin_amdgcn_mfma_f32_16x16x32_bf16(a, b, c, 0, 0, 0);
}
DEVINL float relu(float v) { return v > 0.f ? v : 0.f; }
// swizzled LDS index (u16 units): row r, col c, row-stride 2^sh u16
DEVINL int sxg(int r, int c, int sh) {
  return (r << sh) + (((c >> 3) ^ (r & 7)) << 3) + (c & 7);
}

constexpr int NB = 4096;

// ---------------------------------------------------------------- prep weights
__global__ __launch_bounds__(256) void k_prep_w(
    const float* __restrict__ Wp, const float* __restrict__ W1,
    const float* __restrict__ W2, const float* __restrict__ W3,
    unsigned short* __restrict__ wp1r, unsigned short* __restrict__ wp0r,
    unsigned short* __restrict__ w1p, unsigned short* __restrict__ w2p,
    unsigned short* __restrict__ w3p) {
  int idx = blockIdx.x * 256 + threadIdx.x;
  if (idx < 4096) {
    int p = idx >> 6, i = idx & 63;
    wp1r[p * 64 + i] = f2bf(Wp[(p * 64 + i) * 2 + 1]);
    wp0r[i * 64 + p] = f2bf(Wp[(p * 64 + i) * 2 + 0]);
    return;
  }
  idx -= 4096;
  if (idx < 24576) {  // w1: KS=2, MT=8
    int f = idx >> 9, l = (idx >> 3) & 63, e = idx & 7;
    int mt = f & 7, t = f >> 3, ks = t & 1, k = t >> 1;
    int o = mt * 16 + (l & 15), c = ks * 32 + (l >> 4) * 8 + e;
    w1p[idx] = f2bf(W1[(o * 64 + c) * 3 + k]);
    return;
  }
  idx -= 24576;
  if (idx < 98304) {  // w2: KS=4, MT=16
    int f = idx >> 9, l = (idx >> 3) & 63, e = idx & 7;
    int mt = f & 15, t = f >> 4, ks = t & 3, k = t >> 2;
    int o = mt * 16 + (l & 15), c = ks * 32 + (l >> 4) * 8 + e;
    w2p[idx] = f2bf(W2[(o * 128 + c) * 3 + k]);
    return;
  }
  idx -= 98304;
  if (idx < 196608) {  // w3: KS=8, MT=16
    int f = idx >> 9, l = (idx >> 3) & 63, e = idx & 7;
    int mt = f & 15, t = f >> 4, ks = t & 7, k = t >> 3;
    int o = mt * 16 + (l & 15), c = ks * 32 + (l >> 4) * 8 + e;
    w3p[idx] = f2bf(W3[(o * 256 + c) * 3 + k]);
  }
}

// ---------------------------------------------------------------- Wf1 remap
// grid 416*5: m = bid/5, q = bid%5. Rows 400..415 zero-padded (fc1 M=416).
__global__ __launch_bounds__(256) void k_prep_wf1(const float* __restrict__ wf1,
                                                  unsigned short* __restrict__ wf1r) {
  extern __shared__ unsigned short tls[];  // 8448 u16
  const int m = blockIdx.x / 5, q = blockIdx.x % 5, tid = threadIdx.x;
  unsigned short* dst = wf1r + (size_t)m * 39168;
  if (m >= 400) {
    if (q < 4) {
      for (int idx = tid; idx < 7744; idx += 256) dst[(idx >> 6) * 256 + q * 64 + (idx & 63)] = 0;
    } else {
      for (int idx = tid; idx < 8192; idx += 256) dst[30976 + idx] = 0;
    }
    return;
  }
  if (q < 4) {
    const float* src = wf1 + (size_t)m * 39168 + q * 7744;
    for (int idx = tid; idx < 7744; idx += 256) {
      int o = idx / 121, l = idx - o * 121;
      tls[o * 132 + l] = f2bf(src[idx]);
    }
    __syncthreads();
    for (int idx = tid; idx < 7744; idx += 256) {
      int l = idx >> 6, o = idx & 63;
      dst[l * 256 + q * 64 + o] = tls[o * 132 + l];
    }
  } else {
    const float* src = wf1 + (size_t)m * 39168 + 30976;
    for (int idx = tid; idx < 8192; idx += 256) {
      int il = idx >> 7, cl = idx & 127;
      tls[cl * 66 + il] = f2bf(src[idx]);
    }
    __syncthreads();
    for (int idx = tid; idx < 8192; idx += 256) {
      int cl = idx >> 6, il = idx & 63;
      dst[30976 + idx] = tls[cl * 66 + il];
    }
  }
}

// ---------------------------------------------------------------- conv phase (16 waves)
// wave-grid GM x GN (GM*GN=16); wave = MPW=4 m-tiles x NPW n-tiles (GN*NPW=8).
// A coalesced 1KB frags from packed global; B from swizzled LDS.
template <int CIN, int COUT, int LIN, int LOUT, int SSHI, int SSHO, bool TOGLB>
DEVINL void conv16(const unsigned short* in_lds,
                   const unsigned short* __restrict__ wpack,
                   const float* __restrict__ bias, unsigned short* out_lds,
                   unsigned short* h3, int b, int lane, int wv) {
  constexpr int KS = CIN / 32;
  constexpr int MT = COUT / 16;
  constexpr int MPW = 4;
  constexpr int GM = MT / MPW;
  constexpr int GN = 16 / GM;
  constexpr int NPW = 8 / GN;
  static_assert(GM * GN == 16 && GN * NPW == 8, "");
  const int lr = lane & 15, lq = lane >> 4;
  const int wm = wv / GN, wn = wv % GN;
  f32x4 acc[MPW][NPW];
#pragma unroll
  for (int mi = 0; mi < MPW; ++mi)
#pragma unroll
    for (int ni = 0; ni < NPW; ++ni) acc[mi][ni] = (f32x4){0.f, 0.f, 0.f, 0.f};
#pragma unroll
  for (int k = 0; k < 3; ++k)
#pragma unroll
    for (int ks = 0; ks < KS; ++ks) {
      bf16x8 a[MPW];
#pragma unroll
      for (int mi = 0; mi < MPW; ++mi)
        a[mi] = *(const bf16x8*)(wpack +
                                 (((k * KS + ks) * MT + wm * MPW + mi) << 9) +
                                 lane * 8);
      const int col = ks * 32 + lq * 8;
#pragma unroll
      for (int ni = 0; ni < NPW; ++ni) {
        int l = (wn * NPW + ni) * 16 + lr + k;
        if (l > LIN - 1) l = LIN - 1;  // garbage cols >= LOUT, never stored
        bf16x8 bb = *(const bf16x8*)(in_lds + sxg(l, col, SSHI));
#pragma unroll
        for (int mi = 0; mi < MPW; ++mi)
          acc[mi][ni] = mfma16(a[mi], bb, acc[mi][ni]);
      }
    }
#pragma unroll
  for (int mi = 0; mi < MPW; ++mi) {
    const int o0 = (wm * MPW + mi) * 16 + lq * 4;
    const f32x4 bi = *(const f32x4*)(bias + o0);
#pragma unroll
    for (int ni = 0; ni < NPW; ++ni) {
      const int l = (wn * NPW + ni) * 16 + lr;
      if (l < LOUT) {
        u32x2 pk;
        pk.x = cvtpk(relu(acc[mi][ni][0] + bi[0]), relu(acc[mi][ni][1] + bi[1]));
        pk.y = cvtpk(relu(acc[mi][ni][2] + bi[2]), relu(acc[mi][ni][3] + bi[3]));
        if constexpr (TOGLB)
          *(u32x2*)(h3 + ((size_t)b * LOUT + l) * COUT + o0) = pk;
        else
          *(u32x2*)(out_lds + sxg(l, o0, SSHO)) = pk;
      }
    }
  }
}

// ---------------------------------------------------------------- fused front
// 1024 threads (16 waves -> 4 waves/SIMD at 1 block/CU).
// Regions (u16): A @0     : xs[128]<<6 -> h1s[125]<<7   (16000)
//                B @16000 : h0s[127]<<6 -> h2s[123]<<8  (31488)
// dyn LDS = 94,976 B.
__global__ __launch_bounds__(1024) void k_front(
    const float* __restrict__ x, const unsigned short* __restrict__ wp0r,
    const float* __restrict__ bp, const unsigned short* __restrict__ wp1r,
    const unsigned short* __restrict__ w1p, const float* __restrict__ b1,
    const unsigned short* __restrict__ w2p, const float* __restrict__ b2,
    const unsigned short* __restrict__ w3p, const float* __restrict__ b3,
    unsigned short* __restrict__ h3) {
  extern __shared__ unsigned short lds[];
  unsigned short* xs = lds;
  unsigned short* h1s = lds;
  unsigned short* h0s = lds + 16000;
  unsigned short* h2s = lds + 16000;
  __shared__ float pbase[16][64];
  __shared__ float basel[64];
  const int b = blockIdx.x, tid = threadIdx.x;
  const int lane = tid & 63, wv = tid >> 6, lq = lane >> 4, lr = lane & 15;
  const float* xb = x + (size_t)b * 8192;

  // phase 0: stage x -> xs bf16 [cl][il] swizzled
  for (int idx = tid * 4; idx < 8192; idx += 4096) {
    f32x4 v = *(const f32x4*)(xb + idx);
    int c = idx >> 6, i = idx & 63;
    u32x2 pk;
    pk.x = cvtpk(v[0], v[1]);
    pk.y = cvtpk(v[2], v[3]);
    *(u32x2*)(xs + sxg(c, i, 6)) = pk;
  }
  __syncthreads();

  // phase 0b: base[p] = sum_i Wp0[i][p]*x[b][i]  (xs row 0 unswizzled)
  {
    int p = tid & 63, q = tid >> 6;
    float s = 0.f;
#pragma unroll
    for (int t = 0; t < 4; ++t) {
      int i = q * 4 + t;
      s += bf2f(wp0r[i * 64 + p]) * bf2f(xs[i]);
    }
    pbase[q][p] = s;
  }
  __syncthreads();
  if (tid < 64) {
    float s = bp[tid];
#pragma unroll
    for (int q = 0; q < 16; ++q) s += pbase[q][tid];
    basel[tid] = s;
  }
  __syncthreads();

  // phase 1: pairwise GEMM -> h0s[127][64]; 16 waves: 4m x 4n grid, 2 nt/wave
  {
    const int mt = wv & 3, nh = wv >> 2;
    f32x4 acc[2];
    acc[0] = (f32x4){0.f, 0.f, 0.f, 0.f};
    acc[1] = (f32x4){0.f, 0.f, 0.f, 0.f};
#pragma unroll
    for (int s = 0; s < 2; ++s) {
      bf16x8 a = *(const bf16x8*)(wp1r + (mt * 16 + lr) * 64 + s * 32 + lq * 8);
#pragma unroll
      for (int t = 0; t < 2; ++t) {
        int j = (nh * 2 + t) * 16 + lr;
        int row = j + 1 > 127 ? 127 : j + 1;
        bf16x8 bb = *(const bf16x8*)(xs + sxg(row, s * 32 + lq * 8, 6));
        acc[t] = mfma16(a, bb, acc[t]);
      }
    }
    const int m0 = mt * 16 + lq * 4;
    f32x4 bl;
#pragma unroll
    for (int r = 0; r < 4; ++r) bl[r] = basel[m0 + r];
#pragma unroll
    for (int t = 0; t < 2; ++t) {
      int j = (nh * 2 + t) * 16 + lr;
      if (j < 127) {
        u32x2 pk;
        pk.x = cvtpk(relu(acc[t][0] + bl[0]), relu(acc[t][1] + bl[1]));
        pk.y = cvtpk(relu(acc[t][2] + bl[2]), relu(acc[t][3] + bl[3]));
        *(u32x2*)(h0s + sxg(j, m0, 6)) = pk;
      }
    }
  }
  __syncthreads();

  // conv1 64->128, 127->125 (GM2/GN8/NPW1)
  conv16<64, 128, 127, 125, 6, 7, false>(h0s, w1p, b1, h1s, nullptr, b, lane, wv);
  __syncthreads();
  // conv2 128->256, 125->123 (GM4/GN4/NPW2)
  conv16<128, 256, 125, 123, 7, 8, false>(h1s, w2p, b2, h2s, nullptr, b, lane, wv);
  __syncthreads();
  // conv3 256->256, 123->121 -> global h3 (GM4/GN4/NPW2)
  conv16<256, 256, 123, 121, 8, 0, true>(h2s, w3p, b3, nullptr, h3, b, lane, wv);
}

// ---------------------------------------------------------------- fc1
// 1024 threads (16 waves -> 4 waves/SIMD). Block: M=416 (26 mt, rows 400..415
// zero) x N=128, K64 steps. Wave = 13mt x 1nt (wm=wv>>3, wn=wv&7): per iter
// per wave 2 ds_read_b128 + 26 A-frag loads + 26 MFMA. Double-buffered lB,
// issue-early/write-late staging, 1 barrier/iter. S=16 slices, XCD-pinned.
__global__ __launch_bounds__(1024) void k_fc1(
    const unsigned short* __restrict__ h3, const float* __restrict__ x,
    const unsigned short* __restrict__ wf1r, float* __restrict__ fpart,
    int chunkN, int S) {
  __shared__ unsigned short lB[2][128 * 64];
  const int tid = threadIdx.x;
  const int lane = tid & 63, wv = tid >> 6, lq = lane >> 4, lr = lane & 15;
  const int slice = blockIdx.x % S;
  const int bbase = (blockIdx.x / S) * 128;
  const int per = 612 / S, rem = 612 % S;
  const int c0 = slice * per + (slice < rem ? slice : rem);
  const int c1 = c0 + per + (slice < rem ? 1 : 0);
  const int wm = wv >> 3, wn = wv & 7;

  f32x4 acc[13];
#pragma unroll
  for (int mt = 0; mt < 13; ++mt) acc[mt] = (f32x4){0.f, 0.f, 0.f, 0.f};

  size_t arow[13];
#pragma unroll
  for (int mt = 0; mt < 13; ++mt)
    arow[mt] = (size_t)(wm * 208 + mt * 16 + lr) * 39168;

  // staging: 128 rows x 8 chunks = 1024, exactly one u16x8 per thread
  const int sn = tid >> 3, sch = tid & 7;
  const unsigned short* hrow = h3 + (size_t)(bbase + sn) * 30976 + sch * 8;
  const float* xrow = x + (size_t)(bbase + sn) * 8192 + sch * 8;
  const int woff = (sn << 6) + ((sch ^ (sn & 7)) << 3);

  u32x4 hv;
  f32x4 xv0, xv1;
  bool isx;

#define FC1_GLOAD(KC)                                                     \
  {                                                                       \
    const int k0_ = (KC)*64;                                              \
    isx = (k0_ >= 30976);                                                 \
    if (!isx) {                                                           \
      hv = *(const u32x4*)(hrow + k0_);                                   \
    } else {                                                              \
      xv0 = *(const f32x4*)(xrow + (k0_ - 30976));                        \
      xv1 = *(const f32x4*)(xrow + (k0_ - 30976) + 4);                    \
    }                                                                     \
  }
#define FC1_DSWRITE(BUF)                                                  \
  {                                                                       \
    if (isx) {                                                            \
      hv.x = cvtpk(xv0[0], xv0[1]);                                       \
      hv.y = cvtpk(xv0[2], xv0[3]);                                       \
      hv.z = cvtpk(xv1[0], xv1[1]);                                       \
      hv.w = cvtpk(xv1[2], xv1[3]);                                       \
    }                                                                     \
    *(u32x4*)(lB[BUF] + woff) = hv;                                       \
  }

  FC1_GLOAD(c0)
  FC1_DSWRITE(0)
  __syncthreads();

  const int n = wn * 16 + lr;
  for (int kc = c0; kc < c1; ++kc) {
    const int p = (kc - c0) & 1;
    const int k0 = kc * 64;
    const bool more = (kc + 1 < c1);
    if (more) FC1_GLOAD(kc + 1)

#pragma unroll
    for (int win = 0; win < 2; ++win) {
      const int koff = k0 + win * 32 + lq * 8;
      const int cloc = win * 32 + lq * 8;
      bf16x8 bb = *(const bf16x8*)(lB[p] + sxg(n, cloc, 6));
#pragma unroll
      for (int mt = 0; mt < 13; ++mt) {
        bf16x8 av = *(const bf16x8*)(wf1r + arow[mt] + koff);
        acc[mt] = mfma16(av, bb, acc[mt]);
      }
    }
    if (more) FC1_DSWRITE(p ^ 1)
    __syncthreads();
  }
#undef FC1_GLOAD
#undef FC1_DSWRITE

  const int bb = bbase + wn * 16 + lr;
#pragma unroll
  for (int mt = 0; mt < 13; ++mt) {
    const int m0 = wm * 208 + mt * 16 + lq * 4;
    if (m0 < 400)
      *(f32x4*)(fpart + ((size_t)slice * chunkN + bb) * 400 + m0) = acc[mt];
  }
}

__global__ __launch_bounds__(256) void k_fc1red(const float* __restrict__ fpart,
                                                const float* __restrict__ bf1,
                                                float* __restrict__ fc,
                                                int chunkN, int S) {
  int idx = blockIdx.x * 256 + threadIdx.x;
  if (idx >= chunkN * 400) return;
  int m = idx % 400;
  float s = bf1[m];
  size_t stride = (size_t)chunkN * 400;
#pragma unroll 4
  for (int sl = 0; sl < S; ++sl) s += fpart[(size_t)sl * stride + idx];
  fc[idx] = relu(s);
}

__global__ __launch_bounds__(256) void k_fc2(const float* __restrict__ fc,
                                             const float* __restrict__ wf2,
                                             const float* __restrict__ bf2,
                                             float* __restrict__ out) {
  int b = blockIdx.x * 4 + (threadIdx.x >> 6);
  int lane = threadIdx.x & 63;
  float s = 0.f;
  for (int m = lane; m < 400; m += 64) s += fc[(size_t)b * 400 + m] * wf2[m];
#pragma unroll
  for (int off = 32; off > 0; off >>= 1) s += __shfl_down(s, off, 64);
  if (lane == 0) out[b] = s + bf2[0];
}

// ---------------------------------------------------------------- launch
extern "C" void kernel_launch(void* const* d_in, const int* in_sizes, int n_in,
                              void* d_out, int out_size, void* d_ws, size_t ws_size,
                              hipStream_t stream) {
  const float* x = (const float*)d_in[0];
  const float* Wp = (const float*)d_in[1];
  const float* bp = (const float*)d_in[2];
  const float* W1 = (const float*)d_in[3];
  const float* b1 = (const float*)d_in[4];
  const float* W2 = (const float*)d_in[5];
  const float* b2 = (const float*)d_in[6];
  const float* W3 = (const float*)d_in[7];
  const float* b3 = (const float*)d_in[8];
  const float* Wf1 = (const float*)d_in[9];
  const float* bf1 = (const float*)d_in[10];
  const float* Wf2 = (const float*)d_in[11];
  const float* bf2 = (const float*)d_in[12];
  float* out = (float*)d_out;

  const size_t fixed =
      8192 + 8192 + 49152 + 196608 + 393216 + 416ULL * 39168 * 2;
  const int S = 16;
  static const int cand[3] = {2048, 1024, 512};
  int chunkN = 512;
  for (int i = 0; i < 3; ++i) {
    size_t cn = cand[i];
    size_t need = fixed + cn * 61952ULL + (size_t)S * cn * 1600ULL + cn * 1600ULL;
    if (need <= ws_size) {
      chunkN = cand[i];
      break;
    }
  }
  const int nchunk = NB / chunkN;

  char* ws = (char*)d_ws;
  size_t off = 0;
  unsigned short* h3c = (unsigned short*)(ws + off);
  off += (size_t)chunkN * 61952ULL;
  float* fpart = (float*)(ws + off);
  off += (size_t)S * chunkN * 1600ULL;
  float* fc = (float*)(ws + off);
  off += (size_t)chunkN * 1600ULL;
  unsigned short* wp1r = (unsigned short*)(ws + off);
  off += 8192;
  unsigned short* wp0r = (unsigned short*)(ws + off);
  off += 8192;
  unsigned short* w1p = (unsigned short*)(ws + off);
  off += 49152;
  unsigned short* w2p = (unsigned short*)(ws + off);
  off += 196608;
  unsigned short* w3p = (unsigned short*)(ws + off);
  off += 393216;
  unsigned short* wf1r = (unsigned short*)(ws + off);

  k_prep_w<<<1264, 256, 0, stream>>>(Wp, W1, W2, W3, wp1r, wp0r, w1p, w2p, w3p);
  k_prep_wf1<<<416 * 5, 256, 16896, stream>>>(Wf1, wf1r);

  for (int c = 0; c < nchunk; ++c) {
    const float* xc = x + (size_t)c * chunkN * 8192;
    k_front<<<chunkN, 1024, 94976, stream>>>(xc, wp0r, bp, wp1r, w1p, b1, w2p,
                                             b2, w3p, b3, h3c);
    k_fc1<<<(chunkN / 128) * S, 1024, 0, stream>>>(h3c, xc, wf1r, fpart,
                                                   chunkN, S);
    k_fc1red<<<(chunkN * 400 + 255) / 256, 256, 0, stream>>>(fpart, bf1, fc,
                                                             chunkN, S);
    k_fc2<<<chunkN / 4, 256, 0, stream>>>(fc, Wf2, bf2, out + (size_t)c * chunkN);
  }
}

// Round 13
// 677.571 us; speedup vs baseline: 2.2813x; 2.2813x over previous
//
#include <hip/hip_runtime.h>

// ============================================================================
// CNN3_P r13 = best-known-good union (consolidation after r11/r12 failures):
//  - k_front: r10 exact (512th, cvtpk epilogues, 94,976B LDS, VGPR 88).
//  - k_fc1:   r9 exact  (M=400 25mt, N=128, lB dbuf + A-frag dbuf, S=16).
//  - prep_wf1: r10 exact (400 rows, 5-way split).
//  - r12 lesson: fc1 re-tile diverged on graph replay (nondeterminism) — dropped.
// ============================================================================

typedef __attribute__((ext_vector_type(8))) short bf16x8;
typedef __attribute__((ext_vector_type(4))) float f32x4;
typedef __attribute__((ext_vector_type(8))) unsigned short u16x8;
typedef __attribute__((ext_vector_type(4))) unsigned short u16x4;
typedef __attribute__((ext_vector_type(2))) unsigned int u32x2;
typedef __attribute__((ext_vector_type(4))) unsigned int u32x4;

#define DEVINL __device__ __forceinline__

DEVINL unsigned short f2bf(float f) {
  unsigned u = __builtin_bit_cast(unsigned, f);
  return (unsigned short)((u + 0x7fffu + ((u >> 16) & 1u)) >> 16);  // RNE
}
DEVINL float bf2f(unsigned short h) {
  return __builtin_bit_cast(float, ((unsigned)h) << 16);
}
// packed f32x2 -> bf16x2 (RNE), lo -> bits[15:0]
DEVINL unsigned cvtpk(float lo, float hi) {
  unsigned r;
  asm("v_cvt_pk_bf16_f32 %0, %1, %2" : "=v"(r) : "v"(lo), "v"(hi));
  return r;
}
DEVINL f32x4 mfma16(bf16x8 a, bf16x8 b, f32x4 c) {
  return __builtin_amdgcn_mfma_f32_16x16x32_bf16(a, b, c, 0, 0, 0);
}
DEVINL float relu(float v) { return v > 0.f ? v : 0.f; }
// swizzled LDS index (u16 units): row r, col c, row-stride 2^sh u16
DEVINL int sxg(int r, int c, int sh) {
  return (r << sh) + (((c >> 3) ^ (r & 7)) << 3) + (c & 7);
}

constexpr int NB = 4096;

// ---------------------------------------------------------------- prep weights
__global__ __launch_bounds__(256) void k_prep_w(
    const float* __restrict__ Wp, const float* __restrict__ W1,
    const float* __restrict__ W2, const float* __restrict__ W3,
    unsigned short* __restrict__ wp1r, unsigned short* __restrict__ wp0r,
    unsigned short* __restrict__ w1p, unsigned short* __restrict__ w2p,
    unsigned short* __restrict__ w3p) {
  int idx = blockIdx.x * 256 + threadIdx.x;
  if (idx < 4096) {
    int p = idx >> 6, i = idx & 63;
    wp1r[p * 64 + i] = f2bf(Wp[(p * 64 + i) * 2 + 1]);
    wp0r[i * 64 + p] = f2bf(Wp[(p * 64 + i) * 2 + 0]);
    return;
  }
  idx -= 4096;
  if (idx < 24576) {  // w1: KS=2, MT=8
    int f = idx >> 9, l = (idx >> 3) & 63, e = idx & 7;
    int mt = f & 7, t = f >> 3, ks = t & 1, k = t >> 1;
    int o = mt * 16 + (l & 15), c = ks * 32 + (l >> 4) * 8 + e;
    w1p[idx] = f2bf(W1[(o * 64 + c) * 3 + k]);
    return;
  }
  idx -= 24576;
  if (idx < 98304) {  // w2: KS=4, MT=16
    int f = idx >> 9, l = (idx >> 3) & 63, e = idx & 7;
    int mt = f & 15, t = f >> 4, ks = t & 3, k = t >> 2;
    int o = mt * 16 + (l & 15), c = ks * 32 + (l >> 4) * 8 + e;
    w2p[idx] = f2bf(W2[(o * 128 + c) * 3 + k]);
    return;
  }
  idx -= 98304;
  if (idx < 196608) {  // w3: KS=8, MT=16
    int f = idx >> 9, l = (idx >> 3) & 63, e = idx & 7;
    int mt = f & 15, t = f >> 4, ks = t & 7, k = t >> 3;
    int o = mt * 16 + (l & 15), c = ks * 32 + (l >> 4) * 8 + e;
    w3p[idx] = f2bf(W3[(o * 256 + c) * 3 + k]);
  }
}

// ---------------------------------------------------------------- Wf1 remap
// grid 400*5: m = bid/5, q = bid%5. q<4: h3-part o-range [q*64,(q+1)*64);
// q==4: x-part.
__global__ __launch_bounds__(256) void k_prep_wf1(const float* __restrict__ wf1,
                                                  unsigned short* __restrict__ wf1r) {
  extern __shared__ unsigned short tls[];  // 8448 u16
  const int m = blockIdx.x / 5, q = blockIdx.x % 5, tid = threadIdx.x;
  unsigned short* dst = wf1r + (size_t)m * 39168;
  if (q < 4) {
    const float* src = wf1 + (size_t)m * 39168 + q * 7744;
    for (int idx = tid; idx < 7744; idx += 256) {
      int o = idx / 121, l = idx - o * 121;
      tls[o * 132 + l] = f2bf(src[idx]);
    }
    __syncthreads();
    for (int idx = tid; idx < 7744; idx += 256) {
      int l = idx >> 6, o = idx & 63;
      dst[l * 256 + q * 64 + o] = tls[o * 132 + l];
    }
  } else {
    const float* src = wf1 + (size_t)m * 39168 + 30976;
    for (int idx = tid; idx < 8192; idx += 256) {
      int il = idx >> 7, cl = idx & 127;
      tls[cl * 66 + il] = f2bf(src[idx]);
    }
    __syncthreads();
    for (int idx = tid; idx < 8192; idx += 256) {
      int cl = idx >> 6, il = idx & 63;
      dst[30976 + idx] = tls[cl * 66 + il];
    }
  }
}

// ---------------------------------------------------------------- conv phase (r4)
template <int CIN, int COUT, int LIN, int LOUT, int SSHI, int SSHO, bool TOGLB>
DEVINL void conv16(const unsigned short* in_lds,
                   const unsigned short* __restrict__ wpack,
                   const float* __restrict__ bias, unsigned short* out_lds,
                   unsigned short* h3, int b, int lane, int wv) {
  constexpr int KS = CIN / 32;
  constexpr int MT = COUT / 16;
  constexpr int MPW = MT / 4;
  const int lr = lane & 15, lq = lane >> 4;
  const int wm = wv >> 1, wn = wv & 1;
  f32x4 acc[MPW][4];
#pragma unroll
  for (int mi = 0; mi < MPW; ++mi)
#pragma unroll
    for (int ni = 0; ni < 4; ++ni) acc[mi][ni] = (f32x4){0.f, 0.f, 0.f, 0.f};
#pragma unroll
  for (int k = 0; k < 3; ++k)
#pragma unroll
    for (int ks = 0; ks < KS; ++ks) {
      bf16x8 a[MPW];
#pragma unroll
      for (int mi = 0; mi < MPW; ++mi)
        a[mi] = *(const bf16x8*)(wpack +
                                 (((k * KS + ks) * MT + wm * MPW + mi) << 9) +
                                 lane * 8);
      const int col = ks * 32 + lq * 8;
#pragma unroll
      for (int ni = 0; ni < 4; ++ni) {
        int l = (wn * 4 + ni) * 16 + lr + k;
        if (l > LIN - 1) l = LIN - 1;  // garbage cols >= LOUT, never stored
        bf16x8 bb = *(const bf16x8*)(in_lds + sxg(l, col, SSHI));
#pragma unroll
        for (int mi = 0; mi < MPW; ++mi)
          acc[mi][ni] = mfma16(a[mi], bb, acc[mi][ni]);
      }
    }
#pragma unroll
  for (int mi = 0; mi < MPW; ++mi) {
    const int o0 = (wm * MPW + mi) * 16 + lq * 4;
    const f32x4 bi = *(const f32x4*)(bias + o0);
#pragma unroll
    for (int ni = 0; ni < 4; ++ni) {
      const int l = (wn * 4 + ni) * 16 + lr;
      if (l < LOUT) {
        u32x2 pk;
        pk.x = cvtpk(relu(acc[mi][ni][0] + bi[0]), relu(acc[mi][ni][1] + bi[1]));
        pk.y = cvtpk(relu(acc[mi][ni][2] + bi[2]), relu(acc[mi][ni][3] + bi[3]));
        if constexpr (TOGLB)
          *(u32x2*)(h3 + ((size_t)b * LOUT + l) * COUT + o0) = pk;
        else
          *(u32x2*)(out_lds + sxg(l, o0, SSHO)) = pk;
      }
    }
  }
}

// ---------------------------------------------------------------- fused front (r10)
// Regions (u16): A @0     : xs[128]<<6 -> h1s[125]<<7   (16000)
//                B @16000 : h0s[127]<<6 -> h2s[123]<<8  (31488)
// dyn LDS = 94,976 B.
__global__ __launch_bounds__(512, 1) void k_front(
    const float* __restrict__ x, const unsigned short* __restrict__ wp0r,
    const float* __restrict__ bp, const unsigned short* __restrict__ wp1r,
    const unsigned short* __restrict__ w1p, const float* __restrict__ b1,
    const unsigned short* __restrict__ w2p, const float* __restrict__ b2,
    const unsigned short* __restrict__ w3p, const float* __restrict__ b3,
    unsigned short* __restrict__ h3) {
  extern __shared__ unsigned short lds[];
  unsigned short* xs = lds;
  unsigned short* h1s = lds;
  unsigned short* h0s = lds + 16000;
  unsigned short* h2s = lds + 16000;
  __shared__ float pbase[8][64];
  __shared__ float basel[64];
  const int b = blockIdx.x, tid = threadIdx.x;
  const int lane = tid & 63, wv = tid >> 6, lq = lane >> 4, lr = lane & 15;
  const float* xb = x + (size_t)b * 8192;

  // phase 0: stage x -> xs bf16 [cl][il] swizzled
  for (int idx = tid * 4; idx < 8192; idx += 2048) {
    f32x4 v = *(const f32x4*)(xb + idx);
    int c = idx >> 6, i = idx & 63;
    u32x2 pk;
    pk.x = cvtpk(v[0], v[1]);
    pk.y = cvtpk(v[2], v[3]);
    *(u32x2*)(xs + sxg(c, i, 6)) = pk;
  }
  __syncthreads();

  // phase 0b: base[p] = sum_i Wp0[i][p]*x[b][i]  (xs row 0 unswizzled)
  {
    int p = tid & 63, q = tid >> 6;
    float s = 0.f;
#pragma unroll
    for (int t = 0; t < 8; ++t) {
      int i = q * 8 + t;
      s += bf2f(wp0r[i * 64 + p]) * bf2f(xs[i]);
    }
    pbase[q][p] = s;
  }
  __syncthreads();
  if (tid < 64) {
    float s = bp[tid];
#pragma unroll
    for (int q = 0; q < 8; ++q) s += pbase[q][tid];
    basel[tid] = s;
  }
  __syncthreads();

  // phase 1: pairwise GEMM -> h0s[127][64]
  {
    const int mt = wv & 3, nh = wv >> 2;
    f32x4 acc[4];
#pragma unroll
    for (int t = 0; t < 4; ++t) acc[t] = (f32x4){0.f, 0.f, 0.f, 0.f};
#pragma unroll
    for (int s = 0; s < 2; ++s) {
      bf16x8 a = *(const bf16x8*)(wp1r + (mt * 16 + lr) * 64 + s * 32 + lq * 8);
#pragma unroll
      for (int t = 0; t < 4; ++t) {
        int j = (nh * 4 + t) * 16 + lr;
        int row = j + 1 > 127 ? 127 : j + 1;
        bf16x8 bb = *(const bf16x8*)(xs + sxg(row, s * 32 + lq * 8, 6));
        acc[t] = mfma16(a, bb, acc[t]);
      }
    }
    const int m0 = mt * 16 + lq * 4;
    f32x4 bl;
#pragma unroll
    for (int r = 0; r < 4; ++r) bl[r] = basel[m0 + r];
#pragma unroll
    for (int t = 0; t < 4; ++t) {
      int j = (nh * 4 + t) * 16 + lr;
      if (j < 127) {
        u32x2 pk;
        pk.x = cvtpk(relu(acc[t][0] + bl[0]), relu(acc[t][1] + bl[1]));
        pk.y = cvtpk(relu(acc[t][2] + bl[2]), relu(acc[t][3] + bl[3]));
        *(u32x2*)(h0s + sxg(j, m0, 6)) = pk;
      }
    }
  }
  __syncthreads();

  // conv1 64->128, 127->125
  conv16<64, 128, 127, 125, 6, 7, false>(h0s, w1p, b1, h1s, nullptr, b, lane, wv);
  __syncthreads();
  // conv2 128->256, 125->123
  conv16<128, 256, 125, 123, 7, 8, false>(h1s, w2p, b2, h2s, nullptr, b, lane, wv);
  __syncthreads();
  // conv3 256->256, 123->121 -> global h3 [b][l][o]
  conv16<256, 256, 123, 121, 8, 0, true>(h2s, w3p, b3, nullptr, h3, b, lane, wv);
}

// ---------------------------------------------------------------- fc1 (r9)
// Block 512 th, tile M=400 x N=128, K64 steps. Double-buffered lB (T14
// issue-early/write-late), A-fragment double-buffer, one barrier per K64.
// S=16 slices (1.96MB panels, 2/XCD). grid = 256.
__global__ __launch_bounds__(512, 1) void k_fc1(
    const unsigned short* __restrict__ h3, const float* __restrict__ x,
    const unsigned short* __restrict__ wf1r, float* __restrict__ fpart,
    int chunkN, int S) {
  __shared__ unsigned short lB[2][128 * 64];
  const int tid = threadIdx.x;
  const int lane = tid & 63, wv = tid >> 6, lq = lane >> 4, lr = lane & 15;
  const int slice = blockIdx.x % S;
  const int bbase = (blockIdx.x / S) * 128;
  const int per = 612 / S, rem = 612 % S;
  const int c0 = slice * per + (slice < rem ? slice : rem);
  const int c1 = c0 + per + (slice < rem ? 1 : 0);

  f32x4 acc[3][8], acc24;
#pragma unroll
  for (int mi = 0; mi < 3; ++mi)
#pragma unroll
    for (int nt = 0; nt < 8; ++nt) acc[mi][nt] = (f32x4){0.f, 0.f, 0.f, 0.f};
  acc24 = (f32x4){0.f, 0.f, 0.f, 0.f};

  const size_t arow0 = (size_t)((3 * wv + 0) * 16 + lr) * 39168;
  const size_t arow1 = (size_t)((3 * wv + 1) * 16 + lr) * 39168;
  const size_t arow2 = (size_t)((3 * wv + 2) * 16 + lr) * 39168;
  const size_t arow24 = (size_t)(384 + lr) * 39168;

  // staging coords: thread stages 2 chunks (idx = tid + t*512 over 1024)
  const int sn0 = tid >> 3, sch0 = tid & 7;          // t=0
  const int sn1 = (tid + 512) >> 3, sch1 = tid & 7;  // t=1
  const unsigned short* hrow0 = h3 + (size_t)(bbase + sn0) * 30976 + sch0 * 8;
  const unsigned short* hrow1 = h3 + (size_t)(bbase + sn1) * 30976 + sch1 * 8;
  const float* xrow0 = x + (size_t)(bbase + sn0) * 8192 + sch0 * 8;
  const float* xrow1 = x + (size_t)(bbase + sn1) * 8192 + sch1 * 8;
  const int woff0 = (sn0 << 6) + ((sch0 ^ (sn0 & 7)) << 3);
  const int woff1 = (sn1 << 6) + ((sch1 ^ (sn1 & 7)) << 3);

  u16x8 hv0, hv1;
  f32x4 xv00, xv01, xv10, xv11;
  bool isx;

#define FC1_GLOAD(KC)                                                     \
  {                                                                       \
    const int k0_ = (KC)*64;                                              \
    isx = (k0_ >= 30976);                                                 \
    if (!isx) {                                                           \
      hv0 = *(const u16x8*)(hrow0 + k0_);                                 \
      hv1 = *(const u16x8*)(hrow1 + k0_);                                 \
    } else {                                                              \
      xv00 = *(const f32x4*)(xrow0 + (k0_ - 30976));                      \
      xv01 = *(const f32x4*)(xrow0 + (k0_ - 30976) + 4);                  \
      xv10 = *(const f32x4*)(xrow1 + (k0_ - 30976));                      \
      xv11 = *(const f32x4*)(xrow1 + (k0_ - 30976) + 4);                  \
    }                                                                     \
  }
#define FC1_DSWRITE(BUF)                                                  \
  {                                                                       \
    if (isx) {                                                            \
      _Pragma("unroll") for (int r = 0; r < 4; ++r) {                     \
        hv0[r] = f2bf(xv00[r]);                                           \
        hv0[4 + r] = f2bf(xv01[r]);                                       \
        hv1[r] = f2bf(xv10[r]);                                           \
        hv1[4 + r] = f2bf(xv11[r]);                                       \
      }                                                                   \
    }                                                                     \
    *(u16x8*)(lB[BUF] + woff0) = hv0;                                     \
    *(u16x8*)(lB[BUF] + woff1) = hv1;                                     \
  }
#define FC1_ALOAD(DST, KC)                                                \
  {                                                                       \
    const int ka_ = (KC)*64;                                              \
    _Pragma("unroll") for (int win = 0; win < 2; ++win) {                 \
      const int koff = ka_ + win * 32 + lq * 8;                           \
      DST[win][0] = *(const bf16x8*)(wf1r + arow0 + koff);                \
      DST[win][1] = *(const bf16x8*)(wf1r + arow1 + koff);                \
      DST[win][2] = *(const bf16x8*)(wf1r + arow2 + koff);                \
      DST[win][3] = *(const bf16x8*)(wf1r + arow24 + koff);               \
    }                                                                     \
  }

  bf16x8 aC[2][4], aN[2][4];
  FC1_GLOAD(c0)
  FC1_DSWRITE(0)
  FC1_ALOAD(aC, c0)
  __syncthreads();

#pragma unroll 2
  for (int kc = c0; kc < c1; ++kc) {
    const int p = (kc - c0) & 1;
    const bool more = (kc + 1 < c1);
    if (more) {
      FC1_GLOAD(kc + 1)
      FC1_ALOAD(aN, kc + 1)
    }
#pragma unroll
    for (int win = 0; win < 2; ++win) {
      const int cloc = win * 32 + lq * 8;
#pragma unroll
      for (int nt = 0; nt < 8; ++nt) {
        const int n = nt * 16 + lr;
        bf16x8 bb = *(const bf16x8*)(lB[p] + sxg(n, cloc, 6));
        acc[0][nt] = mfma16(aC[win][0], bb, acc[0][nt]);
        acc[1][nt] = mfma16(aC[win][1], bb, acc[1][nt]);
        acc[2][nt] = mfma16(aC[win][2], bb, acc[2][nt]);
      }
      {
        const int n = wv * 16 + lr;
        bf16x8 bb = *(const bf16x8*)(lB[p] + sxg(n, cloc, 6));
        acc24 = mfma16(aC[win][3], bb, acc24);
      }
    }
    if (more) FC1_DSWRITE(p ^ 1)
    __syncthreads();
#pragma unroll
    for (int w2 = 0; w2 < 2; ++w2)
#pragma unroll
      for (int i = 0; i < 4; ++i) aC[w2][i] = aN[w2][i];
  }
#undef FC1_GLOAD
#undef FC1_DSWRITE
#undef FC1_ALOAD

#pragma unroll
  for (int mi = 0; mi < 3; ++mi) {
    const int m0 = (3 * wv + mi) * 16 + lq * 4;
#pragma unroll
    for (int nt = 0; nt < 8; ++nt) {
      const int bb = bbase + nt * 16 + lr;
      *(f32x4*)(fpart + ((size_t)slice * chunkN + bb) * 400 + m0) = acc[mi][nt];
    }
  }
  {
    const int bb = bbase + wv * 16 + lr;
    *(f32x4*)(fpart + ((size_t)slice * chunkN + bb) * 400 + 384 + lq * 4) = acc24;
  }
}

__global__ __launch_bounds__(256) void k_fc1red(const float* __restrict__ fpart,
                                                const float* __restrict__ bf1,
                                                float* __restrict__ fc,
                                                int chunkN, int S) {
  int idx = blockIdx.x * 256 + threadIdx.x;
  if (idx >= chunkN * 400) return;
  int m = idx % 400;
  float s = bf1[m];
  size_t stride = (size_t)chunkN * 400;
#pragma unroll 4
  for (int sl = 0; sl < S; ++sl) s += fpart[(size_t)sl * stride + idx];
  fc[idx] = relu(s);
}

__global__ __launch_bounds__(256) void k_fc2(const float* __restrict__ fc,
                                             const float* __restrict__ wf2,
                                             const float* __restrict__ bf2,
                                             float* __restrict__ out) {
  int b = blockIdx.x * 4 + (threadIdx.x >> 6);
  int lane = threadIdx.x & 63;
  float s = 0.f;
  for (int m = lane; m < 400; m += 64) s += fc[(size_t)b * 400 + m] * wf2[m];
#pragma unroll
  for (int off = 32; off > 0; off >>= 1) s += __shfl_down(s, off, 64);
  if (lane == 0) out[b] = s + bf2[0];
}

// ---------------------------------------------------------------- launch
extern "C" void kernel_launch(void* const* d_in, const int* in_sizes, int n_in,
                              void* d_out, int out_size, void* d_ws, size_t ws_size,
                              hipStream_t stream) {
  const float* x = (const float*)d_in[0];
  const float* Wp = (const float*)d_in[1];
  const float* bp = (const float*)d_in[2];
  const float* W1 = (const float*)d_in[3];
  const float* b1 = (const float*)d_in[4];
  const float* W2 = (const float*)d_in[5];
  const float* b2 = (const float*)d_in[6];
  const float* W3 = (const float*)d_in[7];
  const float* b3 = (const float*)d_in[8];
  const float* Wf1 = (const float*)d_in[9];
  const float* bf1 = (const float*)d_in[10];
  const float* Wf2 = (const float*)d_in[11];
  const float* bf2 = (const float*)d_in[12];
  float* out = (float*)d_out;

  const size_t fixed =
      8192 + 8192 + 49152 + 196608 + 393216 + 400ULL * 39168 * 2;
  const int S = 16;
  static const int cand[3] = {2048, 1024, 512};
  int chunkN = 512;
  for (int i = 0; i < 3; ++i) {
    size_t cn = cand[i];
    size_t need = fixed + cn * 61952ULL + (size_t)S * cn * 1600ULL + cn * 1600ULL;
    if (need <= ws_size) {
      chunkN = cand[i];
      break;
    }
  }
  const int nchunk = NB / chunkN;

  char* ws = (char*)d_ws;
  size_t off = 0;
  unsigned short* h3c = (unsigned short*)(ws + off);
  off += (size_t)chunkN * 61952ULL;
  float* fpart = (float*)(ws + off);
  off += (size_t)S * chunkN * 1600ULL;
  float* fc = (float*)(ws + off);
  off += (size_t)chunkN * 1600ULL;
  unsigned short* wp1r = (unsigned short*)(ws + off);
  off += 8192;
  unsigned short* wp0r = (unsigned short*)(ws + off);
  off += 8192;
  unsigned short* w1p = (unsigned short*)(ws + off);
  off += 49152;
  unsigned short* w2p = (unsigned short*)(ws + off);
  off += 196608;
  unsigned short* w3p = (unsigned short*)(ws + off);
  off += 393216;
  unsigned short* wf1r = (unsigned short*)(ws + off);

  k_prep_w<<<1264, 256, 0, stream>>>(Wp, W1, W2, W3, wp1r, wp0r, w1p, w2p, w3p);
  k_prep_wf1<<<2000, 256, 16896, stream>>>(Wf1, wf1r);

  for (int c = 0; c < nchunk; ++c) {
    const float* xc = x + (size_t)c * chunkN * 8192;
    k_front<<<chunkN, 512, 94976, stream>>>(xc, wp0r, bp, wp1r, w1p, b1, w2p,
                                            b2, w3p, b3, h3c);
    k_fc1<<<(chunkN / 128) * S, 512, 0, stream>>>(h3c, xc, wf1r, fpart, chunkN, S);
    k_fc1red<<<(chunkN * 400 + 255) / 256, 256, 0, stream>>>(fpart, bf1, fc,
                                                             chunkN, S);
    k_fc2<<<chunkN / 4, 256, 0, stream>>>(fc, Wf2, bf2, out + (size_t)c * chunkN);
  }
}

// Round 14
// 665.332 us; speedup vs baseline: 2.3232x; 1.0184x over previous
//
#include <hip/hip_runtime.h>

// ============================================================================
// CNN3_P r14 = r13 (best validated: 677.6us) + safe tail polish:
//  - k_tail fuses fc1red+fc2 (drops fc buffer + one launch per chunk).
//  - chunkN ladder now tries 4096 first (fewer launch boundaries), falls back.
//  - front (r10/r13) and fc1 (r9/r13) inner loops UNTOUCHED.
// ============================================================================

typedef __attribute__((ext_vector_type(8))) short bf16x8;
typedef __attribute__((ext_vector_type(4))) float f32x4;
typedef __attribute__((ext_vector_type(8))) unsigned short u16x8;
typedef __attribute__((ext_vector_type(4))) unsigned short u16x4;
typedef __attribute__((ext_vector_type(2))) unsigned int u32x2;

#define DEVINL __device__ __forceinline__

DEVINL unsigned short f2bf(float f) {
  unsigned u = __builtin_bit_cast(unsigned, f);
  return (unsigned short)((u + 0x7fffu + ((u >> 16) & 1u)) >> 16);  // RNE
}
DEVINL float bf2f(unsigned short h) {
  return __builtin_bit_cast(float, ((unsigned)h) << 16);
}
// packed f32x2 -> bf16x2 (RNE), lo -> bits[15:0]
DEVINL unsigned cvtpk(float lo, float hi) {
  unsigned r;
  asm("v_cvt_pk_bf16_f32 %0, %1, %2" : "=v"(r) : "v"(lo), "v"(hi));
  return r;
}
DEVINL f32x4 mfma16(bf16x8 a, bf16x8 b, f32x4 c) {
  return __builtin_amdgcn_mfma_f32_16x16x32_bf16(a, b, c, 0, 0, 0);
}
DEVINL float relu(float v) { return v > 0.f ? v : 0.f; }
// swizzled LDS index (u16 units): row r, col c, row-stride 2^sh u16
DEVINL int sxg(int r, int c, int sh) {
  return (r << sh) + (((c >> 3) ^ (r & 7)) << 3) + (c & 7);
}

constexpr int NB = 4096;

// ---------------------------------------------------------------- prep weights
__global__ __launch_bounds__(256) void k_prep_w(
    const float* __restrict__ Wp, const float* __restrict__ W1,
    const float* __restrict__ W2, const float* __restrict__ W3,
    unsigned short* __restrict__ wp1r, unsigned short* __restrict__ wp0r,
    unsigned short* __restrict__ w1p, unsigned short* __restrict__ w2p,
    unsigned short* __restrict__ w3p) {
  int idx = blockIdx.x * 256 + threadIdx.x;
  if (idx < 4096) {
    int p = idx >> 6, i = idx & 63;
    wp1r[p * 64 + i] = f2bf(Wp[(p * 64 + i) * 2 + 1]);
    wp0r[i * 64 + p] = f2bf(Wp[(p * 64 + i) * 2 + 0]);
    return;
  }
  idx -= 4096;
  if (idx < 24576) {  // w1: KS=2, MT=8
    int f = idx >> 9, l = (idx >> 3) & 63, e = idx & 7;
    int mt = f & 7, t = f >> 3, ks = t & 1, k = t >> 1;
    int o = mt * 16 + (l & 15), c = ks * 32 + (l >> 4) * 8 + e;
    w1p[idx] = f2bf(W1[(o * 64 + c) * 3 + k]);
    return;
  }
  idx -= 24576;
  if (idx < 98304) {  // w2: KS=4, MT=16
    int f = idx >> 9, l = (idx >> 3) & 63, e = idx & 7;
    int mt = f & 15, t = f >> 4, ks = t & 3, k = t >> 2;
    int o = mt * 16 + (l & 15), c = ks * 32 + (l >> 4) * 8 + e;
    w2p[idx] = f2bf(W2[(o * 128 + c) * 3 + k]);
    return;
  }
  idx -= 98304;
  if (idx < 196608) {  // w3: KS=8, MT=16
    int f = idx >> 9, l = (idx >> 3) & 63, e = idx & 7;
    int mt = f & 15, t = f >> 4, ks = t & 7, k = t >> 3;
    int o = mt * 16 + (l & 15), c = ks * 32 + (l >> 4) * 8 + e;
    w3p[idx] = f2bf(W3[(o * 256 + c) * 3 + k]);
  }
}

// ---------------------------------------------------------------- Wf1 remap
// grid 400*5: m = bid/5, q = bid%5. q<4: h3-part o-range [q*64,(q+1)*64);
// q==4: x-part.
__global__ __launch_bounds__(256) void k_prep_wf1(const float* __restrict__ wf1,
                                                  unsigned short* __restrict__ wf1r) {
  extern __shared__ unsigned short tls[];  // 8448 u16
  const int m = blockIdx.x / 5, q = blockIdx.x % 5, tid = threadIdx.x;
  unsigned short* dst = wf1r + (size_t)m * 39168;
  if (q < 4) {
    const float* src = wf1 + (size_t)m * 39168 + q * 7744;
    for (int idx = tid; idx < 7744; idx += 256) {
      int o = idx / 121, l = idx - o * 121;
      tls[o * 132 + l] = f2bf(src[idx]);
    }
    __syncthreads();
    for (int idx = tid; idx < 7744; idx += 256) {
      int l = idx >> 6, o = idx & 63;
      dst[l * 256 + q * 64 + o] = tls[o * 132 + l];
    }
  } else {
    const float* src = wf1 + (size_t)m * 39168 + 30976;
    for (int idx = tid; idx < 8192; idx += 256) {
      int il = idx >> 7, cl = idx & 127;
      tls[cl * 66 + il] = f2bf(src[idx]);
    }
    __syncthreads();
    for (int idx = tid; idx < 8192; idx += 256) {
      int cl = idx >> 6, il = idx & 63;
      dst[30976 + idx] = tls[cl * 66 + il];
    }
  }
}

// ---------------------------------------------------------------- conv phase (r4)
template <int CIN, int COUT, int LIN, int LOUT, int SSHI, int SSHO, bool TOGLB>
DEVINL void conv16(const unsigned short* in_lds,
                   const unsigned short* __restrict__ wpack,
                   const float* __restrict__ bias, unsigned short* out_lds,
                   unsigned short* h3, int b, int lane, int wv) {
  constexpr int KS = CIN / 32;
  constexpr int MT = COUT / 16;
  constexpr int MPW = MT / 4;
  const int lr = lane & 15, lq = lane >> 4;
  const int wm = wv >> 1, wn = wv & 1;
  f32x4 acc[MPW][4];
#pragma unroll
  for (int mi = 0; mi < MPW; ++mi)
#pragma unroll
    for (int ni = 0; ni < 4; ++ni) acc[mi][ni] = (f32x4){0.f, 0.f, 0.f, 0.f};
#pragma unroll
  for (int k = 0; k < 3; ++k)
#pragma unroll
    for (int ks = 0; ks < KS; ++ks) {
      bf16x8 a[MPW];
#pragma unroll
      for (int mi = 0; mi < MPW; ++mi)
        a[mi] = *(const bf16x8*)(wpack +
                                 (((k * KS + ks) * MT + wm * MPW + mi) << 9) +
                                 lane * 8);
      const int col = ks * 32 + lq * 8;
#pragma unroll
      for (int ni = 0; ni < 4; ++ni) {
        int l = (wn * 4 + ni) * 16 + lr + k;
        if (l > LIN - 1) l = LIN - 1;  // garbage cols >= LOUT, never stored
        bf16x8 bb = *(const bf16x8*)(in_lds + sxg(l, col, SSHI));
#pragma unroll
        for (int mi = 0; mi < MPW; ++mi)
          acc[mi][ni] = mfma16(a[mi], bb, acc[mi][ni]);
      }
    }
#pragma unroll
  for (int mi = 0; mi < MPW; ++mi) {
    const int o0 = (wm * MPW + mi) * 16 + lq * 4;
    const f32x4 bi = *(const f32x4*)(bias + o0);
#pragma unroll
    for (int ni = 0; ni < 4; ++ni) {
      const int l = (wn * 4 + ni) * 16 + lr;
      if (l < LOUT) {
        u32x2 pk;
        pk.x = cvtpk(relu(acc[mi][ni][0] + bi[0]), relu(acc[mi][ni][1] + bi[1]));
        pk.y = cvtpk(relu(acc[mi][ni][2] + bi[2]), relu(acc[mi][ni][3] + bi[3]));
        if constexpr (TOGLB)
          *(u32x2*)(h3 + ((size_t)b * LOUT + l) * COUT + o0) = pk;
        else
          *(u32x2*)(out_lds + sxg(l, o0, SSHO)) = pk;
      }
    }
  }
}

// ---------------------------------------------------------------- fused front (r10)
// Regions (u16): A @0     : xs[128]<<6 -> h1s[125]<<7   (16000)
//                B @16000 : h0s[127]<<6 -> h2s[123]<<8  (31488)
// dyn LDS = 94,976 B.
__global__ __launch_bounds__(512, 1) void k_front(
    const float* __restrict__ x, const unsigned short* __restrict__ wp0r,
    const float* __restrict__ bp, const unsigned short* __restrict__ wp1r,
    const unsigned short* __restrict__ w1p, const float* __restrict__ b1,
    const unsigned short* __restrict__ w2p, const float* __restrict__ b2,
    const unsigned short* __restrict__ w3p, const float* __restrict__ b3,
    unsigned short* __restrict__ h3) {
  extern __shared__ unsigned short lds[];
  unsigned short* xs = lds;
  unsigned short* h1s = lds;
  unsigned short* h0s = lds + 16000;
  unsigned short* h2s = lds + 16000;
  __shared__ float pbase[8][64];
  __shared__ float basel[64];
  const int b = blockIdx.x, tid = threadIdx.x;
  const int lane = tid & 63, wv = tid >> 6, lq = lane >> 4, lr = lane & 15;
  const float* xb = x + (size_t)b * 8192;

  // phase 0: stage x -> xs bf16 [cl][il] swizzled
  for (int idx = tid * 4; idx < 8192; idx += 2048) {
    f32x4 v = *(const f32x4*)(xb + idx);
    int c = idx >> 6, i = idx & 63;
    u32x2 pk;
    pk.x = cvtpk(v[0], v[1]);
    pk.y = cvtpk(v[2], v[3]);
    *(u32x2*)(xs + sxg(c, i, 6)) = pk;
  }
  __syncthreads();

  // phase 0b: base[p] = sum_i Wp0[i][p]*x[b][i]  (xs row 0 unswizzled)
  {
    int p = tid & 63, q = tid >> 6;
    float s = 0.f;
#pragma unroll
    for (int t = 0; t < 8; ++t) {
      int i = q * 8 + t;
      s += bf2f(wp0r[i * 64 + p]) * bf2f(xs[i]);
    }
    pbase[q][p] = s;
  }
  __syncthreads();
  if (tid < 64) {
    float s = bp[tid];
#pragma unroll
    for (int q = 0; q < 8; ++q) s += pbase[q][tid];
    basel[tid] = s;
  }
  __syncthreads();

  // phase 1: pairwise GEMM -> h0s[127][64]
  {
    const int mt = wv & 3, nh = wv >> 2;
    f32x4 acc[4];
#pragma unroll
    for (int t = 0; t < 4; ++t) acc[t] = (f32x4){0.f, 0.f, 0.f, 0.f};
#pragma unroll
    for (int s = 0; s < 2; ++s) {
      bf16x8 a = *(const bf16x8*)(wp1r + (mt * 16 + lr) * 64 + s * 32 + lq * 8);
#pragma unroll
      for (int t = 0; t < 4; ++t) {
        int j = (nh * 4 + t) * 16 + lr;
        int row = j + 1 > 127 ? 127 : j + 1;
        bf16x8 bb = *(const bf16x8*)(xs + sxg(row, s * 32 + lq * 8, 6));
        acc[t] = mfma16(a, bb, acc[t]);
      }
    }
    const int m0 = mt * 16 + lq * 4;
    f32x4 bl;
#pragma unroll
    for (int r = 0; r < 4; ++r) bl[r] = basel[m0 + r];
#pragma unroll
    for (int t = 0; t < 4; ++t) {
      int j = (nh * 4 + t) * 16 + lr;
      if (j < 127) {
        u32x2 pk;
        pk.x = cvtpk(relu(acc[t][0] + bl[0]), relu(acc[t][1] + bl[1]));
        pk.y = cvtpk(relu(acc[t][2] + bl[2]), relu(acc[t][3] + bl[3]));
        *(u32x2*)(h0s + sxg(j, m0, 6)) = pk;
      }
    }
  }
  __syncthreads();

  // conv1 64->128, 127->125
  conv16<64, 128, 127, 125, 6, 7, false>(h0s, w1p, b1, h1s, nullptr, b, lane, wv);
  __syncthreads();
  // conv2 128->256, 125->123
  conv16<128, 256, 125, 123, 7, 8, false>(h1s, w2p, b2, h2s, nullptr, b, lane, wv);
  __syncthreads();
  // conv3 256->256, 123->121 -> global h3 [b][l][o]
  conv16<256, 256, 123, 121, 8, 0, true>(h2s, w3p, b3, nullptr, h3, b, lane, wv);
}

// ---------------------------------------------------------------- fc1 (r9)
// Block 512 th, tile M=400 x N=128, K64 steps. Double-buffered lB (T14
// issue-early/write-late), A-fragment double-buffer, one barrier per K64.
// S=16 slices (1.96MB panels, 2/XCD).
__global__ __launch_bounds__(512, 1) void k_fc1(
    const unsigned short* __restrict__ h3, const float* __restrict__ x,
    const unsigned short* __restrict__ wf1r, float* __restrict__ fpart,
    int chunkN, int S) {
  __shared__ unsigned short lB[2][128 * 64];
  const int tid = threadIdx.x;
  const int lane = tid & 63, wv = tid >> 6, lq = lane >> 4, lr = lane & 15;
  const int slice = blockIdx.x % S;
  const int bbase = (blockIdx.x / S) * 128;
  const int per = 612 / S, rem = 612 % S;
  const int c0 = slice * per + (slice < rem ? slice : rem);
  const int c1 = c0 + per + (slice < rem ? 1 : 0);

  f32x4 acc[3][8], acc24;
#pragma unroll
  for (int mi = 0; mi < 3; ++mi)
#pragma unroll
    for (int nt = 0; nt < 8; ++nt) acc[mi][nt] = (f32x4){0.f, 0.f, 0.f, 0.f};
  acc24 = (f32x4){0.f, 0.f, 0.f, 0.f};

  const size_t arow0 = (size_t)((3 * wv + 0) * 16 + lr) * 39168;
  const size_t arow1 = (size_t)((3 * wv + 1) * 16 + lr) * 39168;
  const size_t arow2 = (size_t)((3 * wv + 2) * 16 + lr) * 39168;
  const size_t arow24 = (size_t)(384 + lr) * 39168;

  // staging coords: thread stages 2 chunks (idx = tid + t*512 over 1024)
  const int sn0 = tid >> 3, sch0 = tid & 7;          // t=0
  const int sn1 = (tid + 512) >> 3, sch1 = tid & 7;  // t=1
  const unsigned short* hrow0 = h3 + (size_t)(bbase + sn0) * 30976 + sch0 * 8;
  const unsigned short* hrow1 = h3 + (size_t)(bbase + sn1) * 30976 + sch1 * 8;
  const float* xrow0 = x + (size_t)(bbase + sn0) * 8192 + sch0 * 8;
  const float* xrow1 = x + (size_t)(bbase + sn1) * 8192 + sch1 * 8;
  const int woff0 = (sn0 << 6) + ((sch0 ^ (sn0 & 7)) << 3);
  const int woff1 = (sn1 << 6) + ((sch1 ^ (sn1 & 7)) << 3);

  u16x8 hv0, hv1;
  f32x4 xv00, xv01, xv10, xv11;
  bool isx;

#define FC1_GLOAD(KC)                                                     \
  {                                                                       \
    const int k0_ = (KC)*64;                                              \
    isx = (k0_ >= 30976);                                                 \
    if (!isx) {                                                           \
      hv0 = *(const u16x8*)(hrow0 + k0_);                                 \
      hv1 = *(const u16x8*)(hrow1 + k0_);                                 \
    } else {                                                              \
      xv00 = *(const f32x4*)(xrow0 + (k0_ - 30976));                      \
      xv01 = *(const f32x4*)(xrow0 + (k0_ - 30976) + 4);                  \
      xv10 = *(const f32x4*)(xrow1 + (k0_ - 30976));                      \
      xv11 = *(const f32x4*)(xrow1 + (k0_ - 30976) + 4);                  \
    }                                                                     \
  }
#define FC1_DSWRITE(BUF)                                                  \
  {                                                                       \
    if (isx) {                                                            \
      _Pragma("unroll") for (int r = 0; r < 4; ++r) {                     \
        hv0[r] = f2bf(xv00[r]);                                           \
        hv0[4 + r] = f2bf(xv01[r]);                                       \
        hv1[r] = f2bf(xv10[r]);                                           \
        hv1[4 + r] = f2bf(xv11[r]);                                       \
      }                                                                   \
    }                                                                     \
    *(u16x8*)(lB[BUF] + woff0) = hv0;                                     \
    *(u16x8*)(lB[BUF] + woff1) = hv1;                                     \
  }
#define FC1_ALOAD(DST, KC)                                                \
  {                                                                       \
    const int ka_ = (KC)*64;                                              \
    _Pragma("unroll") for (int win = 0; win < 2; ++win) {                 \
      const int koff = ka_ + win * 32 + lq * 8;                           \
      DST[win][0] = *(const bf16x8*)(wf1r + arow0 + koff);                \
      DST[win][1] = *(const bf16x8*)(wf1r + arow1 + koff);                \
      DST[win][2] = *(const bf16x8*)(wf1r + arow2 + koff);                \
      DST[win][3] = *(const bf16x8*)(wf1r + arow24 + koff);               \
    }                                                                     \
  }

  bf16x8 aC[2][4], aN[2][4];
  FC1_GLOAD(c0)
  FC1_DSWRITE(0)
  FC1_ALOAD(aC, c0)
  __syncthreads();

#pragma unroll 2
  for (int kc = c0; kc < c1; ++kc) {
    const int p = (kc - c0) & 1;
    const bool more = (kc + 1 < c1);
    if (more) {
      FC1_GLOAD(kc + 1)
      FC1_ALOAD(aN, kc + 1)
    }
#pragma unroll
    for (int win = 0; win < 2; ++win) {
      const int cloc = win * 32 + lq * 8;
#pragma unroll
      for (int nt = 0; nt < 8; ++nt) {
        const int n = nt * 16 + lr;
        bf16x8 bb = *(const bf16x8*)(lB[p] + sxg(n, cloc, 6));
        acc[0][nt] = mfma16(aC[win][0], bb, acc[0][nt]);
        acc[1][nt] = mfma16(aC[win][1], bb, acc[1][nt]);
        acc[2][nt] = mfma16(aC[win][2], bb, acc[2][nt]);
      }
      {
        const int n = wv * 16 + lr;
        bf16x8 bb = *(const bf16x8*)(lB[p] + sxg(n, cloc, 6));
        acc24 = mfma16(aC[win][3], bb, acc24);
      }
    }
    if (more) FC1_DSWRITE(p ^ 1)
    __syncthreads();
#pragma unroll
    for (int w2 = 0; w2 < 2; ++w2)
#pragma unroll
      for (int i = 0; i < 4; ++i) aC[w2][i] = aN[w2][i];
  }
#undef FC1_GLOAD
#undef FC1_DSWRITE
#undef FC1_ALOAD

#pragma unroll
  for (int mi = 0; mi < 3; ++mi) {
    const int m0 = (3 * wv + mi) * 16 + lq * 4;
#pragma unroll
    for (int nt = 0; nt < 8; ++nt) {
      const int bb = bbase + nt * 16 + lr;
      *(f32x4*)(fpart + ((size_t)slice * chunkN + bb) * 400 + m0) = acc[mi][nt];
    }
  }
  {
    const int bb = bbase + wv * 16 + lr;
    *(f32x4*)(fpart + ((size_t)slice * chunkN + bb) * 400 + 384 + lq * 4) = acc24;
  }
}

// ---------------------------------------------------------------- fused tail
// out[b] = bf2 + sum_m relu(bf1[m] + sum_sl fpart[sl][b][m]) * wf2[m]
// block = 4 samples (4 waves of 64); lane m-strided; wave shfl-reduce.
__global__ __launch_bounds__(256) void k_tail(const float* __restrict__ fpart,
                                              const float* __restrict__ bf1,
                                              const float* __restrict__ wf2,
                                              const float* __restrict__ bf2,
                                              float* __restrict__ out,
                                              int chunkN, int S) {
  const int b = blockIdx.x * 4 + (threadIdx.x >> 6);
  const int lane = threadIdx.x & 63;
  const size_t stride = (size_t)chunkN * 400;
  float acc = 0.f;
  for (int m = lane; m < 400; m += 64) {
    float s = bf1[m];
    const float* p = fpart + (size_t)b * 400 + m;
#pragma unroll 4
    for (int sl = 0; sl < S; ++sl) s += p[(size_t)sl * stride];
    acc += relu(s) * wf2[m];
  }
#pragma unroll
  for (int off = 32; off > 0; off >>= 1) acc += __shfl_down(acc, off, 64);
  if (lane == 0) out[b] = acc + bf2[0];
}

// ---------------------------------------------------------------- launch
extern "C" void kernel_launch(void* const* d_in, const int* in_sizes, int n_in,
                              void* d_out, int out_size, void* d_ws, size_t ws_size,
                              hipStream_t stream) {
  const float* x = (const float*)d_in[0];
  const float* Wp = (const float*)d_in[1];
  const float* bp = (const float*)d_in[2];
  const float* W1 = (const float*)d_in[3];
  const float* b1 = (const float*)d_in[4];
  const float* W2 = (const float*)d_in[5];
  const float* b2 = (const float*)d_in[6];
  const float* W3 = (const float*)d_in[7];
  const float* b3 = (const float*)d_in[8];
  const float* Wf1 = (const float*)d_in[9];
  const float* bf1 = (const float*)d_in[10];
  const float* Wf2 = (const float*)d_in[11];
  const float* bf2 = (const float*)d_in[12];
  float* out = (float*)d_out;

  const size_t fixed =
      8192 + 8192 + 49152 + 196608 + 393216 + 400ULL * 39168 * 2;
  const int S = 16;
  static const int cand[4] = {4096, 2048, 1024, 512};
  int chunkN = 512;
  for (int i = 0; i < 4; ++i) {
    size_t cn = cand[i];
    size_t need = fixed + cn * 61952ULL + (size_t)S * cn * 1600ULL;
    if (need <= ws_size) {
      chunkN = cand[i];
      break;
    }
  }
  const int nchunk = NB / chunkN;

  char* ws = (char*)d_ws;
  size_t off = 0;
  unsigned short* h3c = (unsigned short*)(ws + off);
  off += (size_t)chunkN * 61952ULL;
  float* fpart = (float*)(ws + off);
  off += (size_t)S * chunkN * 1600ULL;
  unsigned short* wp1r = (unsigned short*)(ws + off);
  off += 8192;
  unsigned short* wp0r = (unsigned short*)(ws + off);
  off += 8192;
  unsigned short* w1p = (unsigned short*)(ws + off);
  off += 49152;
  unsigned short* w2p = (unsigned short*)(ws + off);
  off += 196608;
  unsigned short* w3p = (unsigned short*)(ws + off);
  off += 393216;
  unsigned short* wf1r = (unsigned short*)(ws + off);

  k_prep_w<<<1264, 256, 0, stream>>>(Wp, W1, W2, W3, wp1r, wp0r, w1p, w2p, w3p);
  k_prep_wf1<<<2000, 256, 16896, stream>>>(Wf1, wf1r);

  for (int c = 0; c < nchunk; ++c) {
    const float* xc = x + (size_t)c * chunkN * 8192;
    k_front<<<chunkN, 512, 94976, stream>>>(xc, wp0r, bp, wp1r, w1p, b1, w2p,
                                            b2, w3p, b3, h3c);
    k_fc1<<<(chunkN / 128) * S, 512, 0, stream>>>(h3c, xc, wf1r, fpart, chunkN, S);
    k_tail<<<chunkN / 4, 256, 0, stream>>>(fpart, bf1, Wf2, bf2,
                                           out + (size_t)c * chunkN, chunkN, S);
  }
}